// Round 16
// baseline (149.580 us; speedup 1.0000x reference)
//
#include <hip/hip_runtime.h>
#include <hip/hip_fp8.h>

// Pipeline (fp8 att table, fp16 agg table, fp32 accum, MFMA node-GEMM):
//   k_prep : blocks<64: W1 -> W1^T bf16 pre-swizzled; blocks>=64: zero denom+counts
//   k_gemm : g=h@W1 (mfma) -> gh8 (fp8, 128B rows) + hh fp16 copy; tail: hist+rank
//   k_scanA/scanC2 : scan counts -> row_start
//   k_fill0: bsrc[row_start[dst[e]] + rank[e]] = src[e]
//   k_att2 : one dst/sub; chunk-of-8 gathers, NONTEMPORAL (L1-bypass) loads
//   k_norm : hh[s] *= 1/denom[s] in place
//   k_agg  : one dst/sub; chunk-of-8 nt gathers of hh rows

typedef unsigned int uint;
typedef unsigned short ushort;
typedef unsigned char uchar;
typedef __attribute__((ext_vector_type(8))) short short8;
typedef __attribute__((ext_vector_type(4))) float f32x4;
typedef __attribute__((ext_vector_type(2))) float f32x2;
typedef __attribute__((ext_vector_type(2))) uint ux2;
typedef __attribute__((ext_vector_type(4))) uint ux4;

static __device__ __forceinline__ uint pack_f16(float a, float b) {
  _Float16 ha = (_Float16)a, hb = (_Float16)b;
  unsigned short ua = __builtin_bit_cast(unsigned short, ha);
  unsigned short ub = __builtin_bit_cast(unsigned short, hb);
  return ((uint)ub << 16) | ua;
}
static __device__ __forceinline__ float2 unpack_f16(uint u) {
  _Float16 lo = __builtin_bit_cast(_Float16, (unsigned short)(u & 0xffffu));
  _Float16 hi = __builtin_bit_cast(_Float16, (unsigned short)(u >> 16));
  return make_float2((float)lo, (float)hi);
}
static __device__ __forceinline__ ushort f2bf(float x) {
  uint u = __float_as_uint(x);
  u += 0x7fffu + ((u >> 16) & 1u);   // RNE
  return (ushort)(u >> 16);
}

// ---- nontemporal (L1-bypass) load helpers ----
static __device__ __forceinline__ int nt_i32(const int* p) {
  return __builtin_nontemporal_load(p);
}
static __device__ __forceinline__ ux2 nt_u2(const uint* p) {
  return __builtin_nontemporal_load((const ux2*)p);
}
static __device__ __forceinline__ ux4 nt_u4(const uint* p) {
  return __builtin_nontemporal_load((const ux4*)p);
}
static __device__ __forceinline__ void nt_ld2i(const int2* p, int& a, int& b) {
  ux2 v = __builtin_nontemporal_load((const ux2*)p);
  a = (int)v.x; b = (int)v.y;
}

// ---- fp8 e4m3 helpers ----
#if __has_builtin(__builtin_amdgcn_cvt_pk_fp8_f32) && __has_builtin(__builtin_amdgcn_cvt_pk_f32_fp8)
static __device__ __forceinline__ uchar f2fp8(float v) {
  uint u = __builtin_amdgcn_cvt_pk_fp8_f32(v, v, 0u, false);
  return (uchar)(u & 0xFFu);
}
template <bool HI>
static __device__ __forceinline__ float2 fp8x2(uint word) {
  f32x2 r = __builtin_amdgcn_cvt_pk_f32_fp8(word, HI);
  return make_float2(r.x, r.y);
}
#else
static __device__ __forceinline__ uchar f2fp8(float v) {
  __hip_fp8_e4m3 t(v);
  return *(uchar*)&t;
}
static __device__ __forceinline__ float fp8one(uchar b) {
  __hip_fp8_e4m3 t;
  *(uchar*)&t = b;
  return (float)t;
}
template <bool HI>
static __device__ __forceinline__ float2 fp8x2(uint word) {
  uint sh = HI ? 16 : 0;
  return make_float2(fp8one((uchar)(word >> sh)), fp8one((uchar)(word >> (sh + 8))));
}
#endif

// 16-lane sum on the VALU pipe via DPP; row (16 lanes) == sub-group.
static __device__ __forceinline__ float dpp_red16(float x) {
  int v;
  v = __builtin_amdgcn_update_dpp(0, __builtin_bit_cast(int, x), 0xB1, 0xF, 0xF, true);
  x += __builtin_bit_cast(float, v);
  v = __builtin_amdgcn_update_dpp(0, __builtin_bit_cast(int, x), 0x4E, 0xF, 0xF, true);
  x += __builtin_bit_cast(float, v);
  v = __builtin_amdgcn_update_dpp(0, __builtin_bit_cast(int, x), 0x124, 0xF, 0xF, true);
  x += __builtin_bit_cast(float, v);
  v = __builtin_amdgcn_update_dpp(0, __builtin_bit_cast(int, x), 0x128, 0xF, 0xF, true);
  x += __builtin_bit_cast(float, v);
  return x;
}

struct AttC { float c0, c1, c2, c3, c4, c5, c6, c7; float4 w2a, w2b; };

static __device__ __forceinline__ float edge_logit(ux2 u, const AttC& k) {
  float2 f0 = fp8x2<false>(u.x), f1 = fp8x2<true>(u.x);
  float2 f2 = fp8x2<false>(u.y), f3 = fp8x2<true>(u.y);
  float acc = 0.f, t;
  t = fmaxf(f0.x + k.c0, 0.f); acc = fmaf(t, k.w2a.x, acc);
  t = fmaxf(f0.y + k.c1, 0.f); acc = fmaf(t, k.w2a.y, acc);
  t = fmaxf(f1.x + k.c2, 0.f); acc = fmaf(t, k.w2a.z, acc);
  t = fmaxf(f1.y + k.c3, 0.f); acc = fmaf(t, k.w2a.w, acc);
  t = fmaxf(f2.x + k.c4, 0.f); acc = fmaf(t, k.w2b.x, acc);
  t = fmaxf(f2.y + k.c5, 0.f); acc = fmaf(t, k.w2b.y, acc);
  t = fmaxf(f3.x + k.c6, 0.f); acc = fmaf(t, k.w2b.z, acc);
  t = fmaxf(f3.y + k.c7, 0.f); acc = fmaf(t, k.w2b.w, acc);
  return acc;
}

// accumulate wgt * fp16-row into 8 accumulators
static __device__ __forceinline__ void accv(float wgt, ux4 row,
                                            float& a0, float& a1, float& a2, float& a3,
                                            float& a4, float& a5, float& a6, float& a7) {
  float2 f0 = unpack_f16(row.x), f1 = unpack_f16(row.y);
  float2 f2 = unpack_f16(row.z), f3 = unpack_f16(row.w);
  a0 = fmaf(wgt, f0.x, a0); a1 = fmaf(wgt, f0.y, a1);
  a2 = fmaf(wgt, f1.x, a2); a3 = fmaf(wgt, f1.y, a3);
  a4 = fmaf(wgt, f2.x, a4); a5 = fmaf(wgt, f2.y, a5);
  a6 = fmaf(wgt, f3.x, a6); a7 = fmaf(wgt, f3.y, a7);
}

// blocks 0..63: W1 -> W1^T bf16 swizzled; blocks 64+: zero denom+counts
__global__ __launch_bounds__(256) void k_prep(const float* __restrict__ W1,
                                              ushort* __restrict__ w1t_swz,
                                              int* __restrict__ zbase, int zwords) {
  int b = blockIdx.x;
  if (b < 64) {
    int idx = b * 256 + threadIdx.x;
    int n = idx >> 7, k = idx & 127;
    float v = W1[k * 128 + n];
    int byte_off = n * 256 + ((k * 2) ^ ((n & 7) << 4));
    w1t_swz[byte_off >> 1] = f2bf(v);
  } else {
    int i = (b - 64) * 256 + threadIdx.x;
    int stride = (gridDim.x - 64) * 256;
    for (; i < zwords; i += stride) zbase[i] = 0;
  }
}

__global__ __launch_bounds__(256) void k_gemm(const float* __restrict__ h,
                                              const ushort* __restrict__ w1t_swz,
                                              uchar* __restrict__ gh8,
                                              uint4* __restrict__ hh4,
                                              int n_nodes,
                                              const int* __restrict__ dst,
                                              int* __restrict__ counts,
                                              int* __restrict__ rank,
                                              int n_edges, int gemm_blocks) {
  if ((int)blockIdx.x >= gemm_blocks) {
    int hb = blockIdx.x - gemm_blocks;
    int i = hb * 256 + threadIdx.x;
    int stride = (gridDim.x - gemm_blocks) * 256;
    for (int e = i; e < n_edges; e += stride) {
      int r = atomicAdd(&counts[dst[e]], 1);
      rank[e] = r;
    }
    return;
  }
  __shared__ ushort w1s[16384];
  int tid = threadIdx.x;
  {
    const uint4* srcw = (const uint4*)w1t_swz;
    uint4* dstw = (uint4*)w1s;
    #pragma unroll
    for (int i = 0; i < 8; ++i) dstw[tid + 256 * i] = srcw[tid + 256 * i];
  }
  __syncthreads();
  int wave = tid >> 6, lane = tid & 63;
  int tile = blockIdx.x * 4 + wave;
  if (tile * 16 >= n_nodes) return;
  int n0 = tile * 16;
  int l15 = lane & 15, kq = lane >> 4;
  int row = n0 + l15;

  f32x4 acc[8];
  #pragma unroll
  for (int ct = 0; ct < 8; ++ct) acc[ct] = (f32x4){0.f, 0.f, 0.f, 0.f};

  #pragma unroll
  for (int kb = 0; kb < 4; ++kb) {
    const float* hp = &h[(size_t)row * 128 + kb * 32 + kq * 8];
    float4 p0 = *(const float4*)hp;
    float4 p1 = *(const float4*)(hp + 4);
    short8 a;
    a[0] = (short)f2bf(p0.x); a[1] = (short)f2bf(p0.y);
    a[2] = (short)f2bf(p0.z); a[3] = (short)f2bf(p0.w);
    a[4] = (short)f2bf(p1.x); a[5] = (short)f2bf(p1.y);
    a[6] = (short)f2bf(p1.z); a[7] = (short)f2bf(p1.w);
    uint4 hv;
    hv.x = pack_f16(p0.x, p0.y); hv.y = pack_f16(p0.z, p0.w);
    hv.z = pack_f16(p1.x, p1.y); hv.w = pack_f16(p1.z, p1.w);
    hh4[(size_t)row * 16 + kb * 4 + kq] = hv;
    #pragma unroll
    for (int ct = 0; ct < 8; ++ct) {
      int n = ct * 16 + l15;
      int byte_off = n * 256 + (((kb * 64) + kq * 16) ^ ((n & 7) << 4));
      short8 b = *(const short8*)((const char*)w1s + byte_off);
      acc[ct] = __builtin_amdgcn_mfma_f32_16x16x32_bf16(a, b, acc[ct], 0, 0, 0);
    }
  }
  #pragma unroll
  for (int ct = 0; ct < 8; ++ct) {
    #pragma unroll
    for (int r = 0; r < 4; ++r) {
      int orow = n0 + kq * 4 + r;
      gh8[(size_t)orow * 128 + ct * 16 + l15] = f2fp8(acc[ct][r]);
    }
  }
}

__global__ __launch_bounds__(256) void k_scanA(const int* __restrict__ counts,
                                               int* __restrict__ partials,
                                               int n, int chunk) {
  __shared__ int red[256];
  int b = blockIdx.x, t = threadIdx.x;
  int idx = b * chunk + t;
  red[t] = (t < chunk && idx < n) ? counts[idx] : 0;
  __syncthreads();
  for (int off = 128; off > 0; off >>= 1) {
    if (t < off) red[t] += red[t + off];
    __syncthreads();
  }
  if (t == 0) partials[b] = red[0];
}

__global__ __launch_bounds__(256) void k_scanC2(const int* __restrict__ counts,
                                                const int* __restrict__ partials,
                                                int* __restrict__ row_start,
                                                int n, int chunk, int total) {
  __shared__ int bp[256];
  __shared__ int p[256];
  int b = blockIdx.x, t = threadIdx.x;
  bp[t] = partials[t];
  __syncthreads();
  #pragma unroll
  for (int off = 1; off < 256; off <<= 1) {
    int v = (t >= off) ? bp[t - off] : 0;
    __syncthreads();
    bp[t] += v;
    __syncthreads();
  }
  int base = (b == 0) ? 0 : bp[b - 1];
  int idx = b * chunk + t;
  bool ok = (t < chunk && idx < n);
  int orig = ok ? counts[idx] : 0;
  p[t] = orig;
  __syncthreads();
  #pragma unroll
  for (int off = 1; off < 256; off <<= 1) {
    int v = (t >= off) ? p[t - off] : 0;
    __syncthreads();
    p[t] += v;
    __syncthreads();
  }
  if (ok) row_start[idx] = base + p[t] - orig;
  if (b == 0 && t == 0) row_start[n] = total;
}

__global__ __launch_bounds__(256) void k_fill0(const int* __restrict__ src,
                                               const int* __restrict__ dst,
                                               const int* __restrict__ row_start,
                                               const int* __restrict__ rank,
                                               int* __restrict__ bsrc,
                                               int n_edges) {
  int i = blockIdx.x * blockDim.x + threadIdx.x;
  int stride = gridDim.x * blockDim.x;
  for (int e = i; e < n_edges; e += stride) {
    bsrc[row_start[dst[e]] + rank[e]] = src[e];
  }
}

// one dst per 16-lane sub; chunks of 8; NONTEMPORAL loads throughout
__global__ __launch_bounds__(256) void k_att2(const uint* __restrict__ gh8v,
                                              const int* __restrict__ bsrc,
                                              const int* __restrict__ row_start,
                                              const float* __restrict__ b1,
                                              const float* __restrict__ W2,
                                              const float* __restrict__ b2,
                                              int2* __restrict__ bucket,
                                              float* __restrict__ denom,
                                              int n_nodes) {
  int lane = threadIdx.x & 63;
  int sub = lane >> 4, l16 = lane & 15;
  int wavei = threadIdx.x >> 6;
  int d = blockIdx.x * 16 + wavei * 4 + sub;
  int beg = 0, end = 0;
  if (d < n_nodes) { beg = row_start[d]; end = row_start[d + 1]; }
  float4 b1a = *(const float4*)&b1[l16 * 8];
  float4 b1b = *(const float4*)&b1[l16 * 8 + 4];
  AttC K;
  K.w2a = *(const float4*)&W2[l16 * 8];
  K.w2b = *(const float4*)&W2[l16 * 8 + 4];
  float b2v = b2[0];
  K.c0 = K.c1 = K.c2 = K.c3 = K.c4 = K.c5 = K.c6 = K.c7 = 0.f;
  if (beg < end) {
    ux2 ud = nt_u2(&gh8v[((size_t)d * 16 + l16) * 2]);
    float2 da = fp8x2<false>(ud.x), db = fp8x2<true>(ud.x);
    float2 dc = fp8x2<false>(ud.y), dd = fp8x2<true>(ud.y);
    K.c0 = b1a.x - da.x; K.c1 = b1a.y - da.y; K.c2 = b1a.z - db.x; K.c3 = b1a.w - db.y;
    K.c4 = b1b.x - dc.x; K.c5 = b1b.y - dc.y; K.c6 = b1b.z - dd.x; K.c7 = b1b.w - dd.y;
  }
  uint nn = (uint)n_nodes;
  for (int base = beg; base < end; base += 8) {
    int s0 = nt_i32(&bsrc[base + 0]), s1 = nt_i32(&bsrc[base + 1]);
    int s2 = nt_i32(&bsrc[base + 2]), s3 = nt_i32(&bsrc[base + 3]);
    int s4 = nt_i32(&bsrc[base + 4]), s5 = nt_i32(&bsrc[base + 5]);
    int s6 = nt_i32(&bsrc[base + 6]), s7 = nt_i32(&bsrc[base + 7]);
    s0 = ((uint)s0 < nn) ? s0 : 0;  s1 = ((uint)s1 < nn) ? s1 : 0;
    s2 = ((uint)s2 < nn) ? s2 : 0;  s3 = ((uint)s3 < nn) ? s3 : 0;
    s4 = ((uint)s4 < nn) ? s4 : 0;  s5 = ((uint)s5 < nn) ? s5 : 0;
    s6 = ((uint)s6 < nn) ? s6 : 0;  s7 = ((uint)s7 < nn) ? s7 : 0;
    ux2 u0 = nt_u2(&gh8v[((size_t)s0 * 16 + l16) * 2]);
    ux2 u1 = nt_u2(&gh8v[((size_t)s1 * 16 + l16) * 2]);
    ux2 u2 = nt_u2(&gh8v[((size_t)s2 * 16 + l16) * 2]);
    ux2 u3 = nt_u2(&gh8v[((size_t)s3 * 16 + l16) * 2]);
    ux2 u4 = nt_u2(&gh8v[((size_t)s4 * 16 + l16) * 2]);
    ux2 u5 = nt_u2(&gh8v[((size_t)s5 * 16 + l16) * 2]);
    ux2 u6 = nt_u2(&gh8v[((size_t)s6 * 16 + l16) * 2]);
    ux2 u7 = nt_u2(&gh8v[((size_t)s7 * 16 + l16) * 2]);
    float a0 = dpp_red16(edge_logit(u0, K));
    float a1 = dpp_red16(edge_logit(u1, K));
    float a2 = dpp_red16(edge_logit(u2, K));
    float a3 = dpp_red16(edge_logit(u3, K));
    float a4 = dpp_red16(edge_logit(u4, K));
    float a5 = dpp_red16(edge_logit(u5, K));
    float a6 = dpp_red16(edge_logit(u6, K));
    float a7 = dpp_red16(edge_logit(u7, K));
    if (l16 == 0) {
      float aa[8] = {a0, a1, a2, a3, a4, a5, a6, a7};
      int ss[8] = {s0, s1, s2, s3, s4, s5, s6, s7};
      #pragma unroll
      for (int j = 0; j < 8; ++j) {
        if (base + j < end) {
          float a = fmaxf(aa[j] + b2v, 0.f);
          a = 1.f / (1.f + __expf(-a));
          bucket[base + j] = make_int2(ss[j], __float_as_int(a));
          atomicAdd(&denom[ss[j]], a);
        }
      }
    }
  }
}

// hh[s] *= 1/denom[s] in place (node-parallel, coalesced)
__global__ __launch_bounds__(256) void k_norm(uint4* __restrict__ hh4,
                                              const float* __restrict__ denom,
                                              int n_nodes) {
  int i = blockIdx.x * 256 + threadIdx.x;
  if (i >= n_nodes * 16) return;
  int node = i >> 4;
  float inv = 1.f / denom[node];
  uint4 v = hh4[i];
  float2 f0 = unpack_f16(v.x), f1 = unpack_f16(v.y);
  float2 f2 = unpack_f16(v.z), f3 = unpack_f16(v.w);
  v.x = pack_f16(f0.x * inv, f0.y * inv);
  v.y = pack_f16(f1.x * inv, f1.y * inv);
  v.z = pack_f16(f2.x * inv, f2.y * inv);
  v.w = pack_f16(f3.x * inv, f3.y * inv);
  hh4[i] = v;
}

// one dst per sub; chunks of 8; nt loads for bucket stream + hh gathers
__global__ __launch_bounds__(256) void k_agg(const uint* __restrict__ hhw,
                                             const int* __restrict__ row_start,
                                             const int2* __restrict__ bucket,
                                             float* __restrict__ out, int n_nodes) {
  int lane = threadIdx.x & 63;
  int sub = lane >> 4, l16 = lane & 15;
  int wavei = threadIdx.x >> 6;
  int d = blockIdx.x * 16 + wavei * 4 + sub;
  int beg = 0, end = 0;
  if (d < n_nodes) { beg = row_start[d]; end = row_start[d + 1]; }
  float a0 = 0.f, a1 = 0.f, a2 = 0.f, a3 = 0.f;
  float a4 = 0.f, a5 = 0.f, a6 = 0.f, a7 = 0.f;
  uint nn = (uint)n_nodes;
  for (int base = beg; base < end; base += 8) {
    int s0, s1, s2, s3, s4, s5, s6, s7;
    int q0, q1, q2, q3, q4, q5, q6, q7;
    nt_ld2i(&bucket[base + 0], s0, q0); nt_ld2i(&bucket[base + 1], s1, q1);
    nt_ld2i(&bucket[base + 2], s2, q2); nt_ld2i(&bucket[base + 3], s3, q3);
    nt_ld2i(&bucket[base + 4], s4, q4); nt_ld2i(&bucket[base + 5], s5, q5);
    nt_ld2i(&bucket[base + 6], s6, q6); nt_ld2i(&bucket[base + 7], s7, q7);
    s0 = ((uint)s0 < nn) ? s0 : 0;  s1 = ((uint)s1 < nn) ? s1 : 0;
    s2 = ((uint)s2 < nn) ? s2 : 0;  s3 = ((uint)s3 < nn) ? s3 : 0;
    s4 = ((uint)s4 < nn) ? s4 : 0;  s5 = ((uint)s5 < nn) ? s5 : 0;
    s6 = ((uint)s6 < nn) ? s6 : 0;  s7 = ((uint)s7 < nn) ? s7 : 0;
    ux4 v0 = nt_u4(&hhw[((size_t)s0 * 16 + l16) * 4]);
    ux4 v1 = nt_u4(&hhw[((size_t)s1 * 16 + l16) * 4]);
    ux4 v2 = nt_u4(&hhw[((size_t)s2 * 16 + l16) * 4]);
    ux4 v3 = nt_u4(&hhw[((size_t)s3 * 16 + l16) * 4]);
    ux4 v4 = nt_u4(&hhw[((size_t)s4 * 16 + l16) * 4]);
    ux4 v5 = nt_u4(&hhw[((size_t)s5 * 16 + l16) * 4]);
    ux4 v6 = nt_u4(&hhw[((size_t)s6 * 16 + l16) * 4]);
    ux4 v7 = nt_u4(&hhw[((size_t)s7 * 16 + l16) * 4]);
    float w0 = (base + 0 < end) ? __int_as_float(q0) : 0.f;
    float w1 = (base + 1 < end) ? __int_as_float(q1) : 0.f;
    float w2 = (base + 2 < end) ? __int_as_float(q2) : 0.f;
    float w3 = (base + 3 < end) ? __int_as_float(q3) : 0.f;
    float w4 = (base + 4 < end) ? __int_as_float(q4) : 0.f;
    float w5 = (base + 5 < end) ? __int_as_float(q5) : 0.f;
    float w6 = (base + 6 < end) ? __int_as_float(q6) : 0.f;
    float w7 = (base + 7 < end) ? __int_as_float(q7) : 0.f;
    accv(w0, v0, a0, a1, a2, a3, a4, a5, a6, a7);
    accv(w1, v1, a0, a1, a2, a3, a4, a5, a6, a7);
    accv(w2, v2, a0, a1, a2, a3, a4, a5, a6, a7);
    accv(w3, v3, a0, a1, a2, a3, a4, a5, a6, a7);
    accv(w4, v4, a0, a1, a2, a3, a4, a5, a6, a7);
    accv(w5, v5, a0, a1, a2, a3, a4, a5, a6, a7);
    accv(w6, v6, a0, a1, a2, a3, a4, a5, a6, a7);
    accv(w7, v7, a0, a1, a2, a3, a4, a5, a6, a7);
  }
  if (d < n_nodes) {
    *(float4*)&out[(size_t)d * 128 + l16 * 8]     = make_float4(a0, a1, a2, a3);
    *(float4*)&out[(size_t)d * 128 + l16 * 8 + 4] = make_float4(a4, a5, a6, a7);
  }
}

extern "C" void kernel_launch(void* const* d_in, const int* in_sizes, int n_in,
                              void* d_out, int out_size, void* d_ws, size_t ws_size,
                              hipStream_t stream) {
  const float* h   = (const float*)d_in[0];
  const int*   src = (const int*)d_in[1];
  const int*   dst = (const int*)d_in[2];
  const float* W1  = (const float*)d_in[3];
  const float* b1  = (const float*)d_in[4];
  const float* W2  = (const float*)d_in[5];
  const float* b2  = (const float*)d_in[6];
  float* out = (float*)d_out;

  int n_nodes = in_sizes[0] / 128;
  int n_edges = in_sizes[1];

  char* ws = (char*)d_ws;
  uchar*  gh8       = (uchar*)ws;                           // n*128 bytes (fp8 rows)
  uint*   hh        = (uint*)(ws + (size_t)n_nodes * 128);  // n*64 uints (fp16 rows)
  float*  denom     = (float*)(hh + (size_t)n_nodes * 64);  // n
  int*    counts    = (int*)(denom + n_nodes);              // n
  int*    row_start = counts + n_nodes;                     // n+1
  int*    partials  = row_start + n_nodes + 1;              // 256
  ushort* w1t       = (ushort*)(partials + 256);            // 16384 (32 KiB)
  int2*   bucket    = (int2*)(((uintptr_t)(w1t + 16384) + 15) & ~(uintptr_t)15);  // E
  int*    bsrc      = (int*)(bucket + n_edges);             // E
  int*    rank      = bsrc + n_edges;                       // E (bsrc chunk overreads land here)

  int chunk = (n_nodes + 255) / 256;
  int n_tiles = (n_nodes + 15) / 16;
  int gemm_blocks = (n_tiles + 3) / 4;
  int nblk16 = (n_nodes + 15) / 16;
  k_prep  <<<64 + 16, 256, 0, stream>>>(W1, w1t, (int*)denom, 2 * n_nodes);
  k_gemm  <<<gemm_blocks + 256, 256, 0, stream>>>(h, w1t, gh8, (uint4*)hh, n_nodes,
                                                  dst, counts, rank, n_edges, gemm_blocks);
  k_scanA <<<256, 256, 0, stream>>>(counts, partials, n_nodes, chunk);
  k_scanC2<<<256, 256, 0, stream>>>(counts, partials, row_start, n_nodes, chunk, n_edges);
  k_fill0 <<<1024, 256, 0, stream>>>(src, dst, row_start, rank, bsrc, n_edges);
  k_att2  <<<nblk16, 256, 0, stream>>>((const uint*)gh8, bsrc, row_start, b1, W2, b2,
                                       bucket, denom, n_nodes);
  k_norm  <<<(n_nodes * 16 + 255) / 256, 256, 0, stream>>>((uint4*)hh, denom, n_nodes);
  k_agg   <<<nblk16, 256, 0, stream>>>((const uint*)hh, row_start, bucket, out, n_nodes);
}

// Round 17
// 131.518 us; speedup vs baseline: 1.1373x; 1.1373x over previous
//
#include <hip/hip_runtime.h>
#include <hip/hip_fp8.h>

// Pipeline (fp8 att table, fp16 agg table, fp32 accum, MFMA node-GEMM):
//   k_prep : blocks<64: W1 -> W1^T bf16 pre-swizzled; blocks>=64: zero denom+counts
//   k_gemm : g=h@W1 (mfma) -> gh8 (fp8, 128B rows) + hh fp16 copy; tail: hist+rank
//   k_scanA/scanC2 : scan counts -> row_start
//   k_fill0: bsrc[row_start[dst[e]] + rank[e]] = src[e]
//   k_att2 : one dst/sub; chunk-of-8: uniform index loads -> 8 gathers in flight;
//            DPP reduce; bucket[j]=(s,att); denom[s]+=att
//   k_norm : hh[s] *= 1/denom[s] in place (kills k_agg's dependent denom load)
//   k_agg  : one dst/sub; chunk-of-8 uniform bucket loads -> 8 hh gathers in flight

typedef unsigned int uint;
typedef unsigned short ushort;
typedef unsigned char uchar;
typedef __attribute__((ext_vector_type(8))) short short8;
typedef __attribute__((ext_vector_type(4))) float f32x4;
typedef __attribute__((ext_vector_type(2))) float f32x2;

static __device__ __forceinline__ uint pack_f16(float a, float b) {
  _Float16 ha = (_Float16)a, hb = (_Float16)b;
  unsigned short ua = __builtin_bit_cast(unsigned short, ha);
  unsigned short ub = __builtin_bit_cast(unsigned short, hb);
  return ((uint)ub << 16) | ua;
}
static __device__ __forceinline__ float2 unpack_f16(uint u) {
  _Float16 lo = __builtin_bit_cast(_Float16, (unsigned short)(u & 0xffffu));
  _Float16 hi = __builtin_bit_cast(_Float16, (unsigned short)(u >> 16));
  return make_float2((float)lo, (float)hi);
}
static __device__ __forceinline__ ushort f2bf(float x) {
  uint u = __float_as_uint(x);
  u += 0x7fffu + ((u >> 16) & 1u);   // RNE
  return (ushort)(u >> 16);
}

// ---- fp8 e4m3 helpers ----
#if __has_builtin(__builtin_amdgcn_cvt_pk_fp8_f32) && __has_builtin(__builtin_amdgcn_cvt_pk_f32_fp8)
static __device__ __forceinline__ uchar f2fp8(float v) {
  uint u = __builtin_amdgcn_cvt_pk_fp8_f32(v, v, 0u, false);
  return (uchar)(u & 0xFFu);
}
template <bool HI>
static __device__ __forceinline__ float2 fp8x2(uint word) {
  f32x2 r = __builtin_amdgcn_cvt_pk_f32_fp8(word, HI);
  return make_float2(r.x, r.y);
}
#else
static __device__ __forceinline__ uchar f2fp8(float v) {
  __hip_fp8_e4m3 t(v);
  return *(uchar*)&t;
}
static __device__ __forceinline__ float fp8one(uchar b) {
  __hip_fp8_e4m3 t;
  *(uchar*)&t = b;
  return (float)t;
}
template <bool HI>
static __device__ __forceinline__ float2 fp8x2(uint word) {
  uint sh = HI ? 16 : 0;
  return make_float2(fp8one((uchar)(word >> sh)), fp8one((uchar)(word >> (sh + 8))));
}
#endif

// 16-lane sum on the VALU pipe via DPP; row (16 lanes) == sub-group.
static __device__ __forceinline__ float dpp_red16(float x) {
  int v;
  v = __builtin_amdgcn_update_dpp(0, __builtin_bit_cast(int, x), 0xB1, 0xF, 0xF, true);
  x += __builtin_bit_cast(float, v);
  v = __builtin_amdgcn_update_dpp(0, __builtin_bit_cast(int, x), 0x4E, 0xF, 0xF, true);
  x += __builtin_bit_cast(float, v);
  v = __builtin_amdgcn_update_dpp(0, __builtin_bit_cast(int, x), 0x124, 0xF, 0xF, true);
  x += __builtin_bit_cast(float, v);
  v = __builtin_amdgcn_update_dpp(0, __builtin_bit_cast(int, x), 0x128, 0xF, 0xF, true);
  x += __builtin_bit_cast(float, v);
  return x;
}

struct AttC { float c0, c1, c2, c3, c4, c5, c6, c7; float4 w2a, w2b; };

static __device__ __forceinline__ float edge_logit(uint2 u, const AttC& k) {
  float2 f0 = fp8x2<false>(u.x), f1 = fp8x2<true>(u.x);
  float2 f2 = fp8x2<false>(u.y), f3 = fp8x2<true>(u.y);
  float acc = 0.f, t;
  t = fmaxf(f0.x + k.c0, 0.f); acc = fmaf(t, k.w2a.x, acc);
  t = fmaxf(f0.y + k.c1, 0.f); acc = fmaf(t, k.w2a.y, acc);
  t = fmaxf(f1.x + k.c2, 0.f); acc = fmaf(t, k.w2a.z, acc);
  t = fmaxf(f1.y + k.c3, 0.f); acc = fmaf(t, k.w2a.w, acc);
  t = fmaxf(f2.x + k.c4, 0.f); acc = fmaf(t, k.w2b.x, acc);
  t = fmaxf(f2.y + k.c5, 0.f); acc = fmaf(t, k.w2b.y, acc);
  t = fmaxf(f3.x + k.c6, 0.f); acc = fmaf(t, k.w2b.z, acc);
  t = fmaxf(f3.y + k.c7, 0.f); acc = fmaf(t, k.w2b.w, acc);
  return acc;
}

// accumulate wgt * fp16-row into 8 accumulators (function, not macro!)
static __device__ __forceinline__ void accv(float wgt, uint4 row,
                                            float& a0, float& a1, float& a2, float& a3,
                                            float& a4, float& a5, float& a6, float& a7) {
  float2 f0 = unpack_f16(row.x), f1 = unpack_f16(row.y);
  float2 f2 = unpack_f16(row.z), f3 = unpack_f16(row.w);
  a0 = fmaf(wgt, f0.x, a0); a1 = fmaf(wgt, f0.y, a1);
  a2 = fmaf(wgt, f1.x, a2); a3 = fmaf(wgt, f1.y, a3);
  a4 = fmaf(wgt, f2.x, a4); a5 = fmaf(wgt, f2.y, a5);
  a6 = fmaf(wgt, f3.x, a6); a7 = fmaf(wgt, f3.y, a7);
}

// blocks 0..63: W1 -> W1^T bf16 swizzled; blocks 64+: zero denom+counts
__global__ __launch_bounds__(256) void k_prep(const float* __restrict__ W1,
                                              ushort* __restrict__ w1t_swz,
                                              int* __restrict__ zbase, int zwords) {
  int b = blockIdx.x;
  if (b < 64) {
    int idx = b * 256 + threadIdx.x;
    int n = idx >> 7, k = idx & 127;
    float v = W1[k * 128 + n];
    int byte_off = n * 256 + ((k * 2) ^ ((n & 7) << 4));
    w1t_swz[byte_off >> 1] = f2bf(v);
  } else {
    int i = (b - 64) * 256 + threadIdx.x;
    int stride = (gridDim.x - 64) * 256;
    for (; i < zwords; i += stride) zbase[i] = 0;
  }
}

__global__ __launch_bounds__(256) void k_gemm(const float* __restrict__ h,
                                              const ushort* __restrict__ w1t_swz,
                                              uchar* __restrict__ gh8,
                                              uint4* __restrict__ hh4,
                                              int n_nodes,
                                              const int* __restrict__ dst,
                                              int* __restrict__ counts,
                                              int* __restrict__ rank,
                                              int n_edges, int gemm_blocks) {
  if ((int)blockIdx.x >= gemm_blocks) {
    int hb = blockIdx.x - gemm_blocks;
    int i = hb * 256 + threadIdx.x;
    int stride = (gridDim.x - gemm_blocks) * 256;
    for (int e = i; e < n_edges; e += stride) {
      int r = atomicAdd(&counts[dst[e]], 1);
      rank[e] = r;
    }
    return;
  }
  __shared__ ushort w1s[16384];
  int tid = threadIdx.x;
  {
    const uint4* srcw = (const uint4*)w1t_swz;
    uint4* dstw = (uint4*)w1s;
    #pragma unroll
    for (int i = 0; i < 8; ++i) dstw[tid + 256 * i] = srcw[tid + 256 * i];
  }
  __syncthreads();
  int wave = tid >> 6, lane = tid & 63;
  int tile = blockIdx.x * 4 + wave;
  if (tile * 16 >= n_nodes) return;
  int n0 = tile * 16;
  int l15 = lane & 15, kq = lane >> 4;
  int row = n0 + l15;

  f32x4 acc[8];
  #pragma unroll
  for (int ct = 0; ct < 8; ++ct) acc[ct] = (f32x4){0.f, 0.f, 0.f, 0.f};

  #pragma unroll
  for (int kb = 0; kb < 4; ++kb) {
    const float* hp = &h[(size_t)row * 128 + kb * 32 + kq * 8];
    float4 p0 = *(const float4*)hp;
    float4 p1 = *(const float4*)(hp + 4);
    short8 a;
    a[0] = (short)f2bf(p0.x); a[1] = (short)f2bf(p0.y);
    a[2] = (short)f2bf(p0.z); a[3] = (short)f2bf(p0.w);
    a[4] = (short)f2bf(p1.x); a[5] = (short)f2bf(p1.y);
    a[6] = (short)f2bf(p1.z); a[7] = (short)f2bf(p1.w);
    uint4 hv;
    hv.x = pack_f16(p0.x, p0.y); hv.y = pack_f16(p0.z, p0.w);
    hv.z = pack_f16(p1.x, p1.y); hv.w = pack_f16(p1.z, p1.w);
    hh4[(size_t)row * 16 + kb * 4 + kq] = hv;
    #pragma unroll
    for (int ct = 0; ct < 8; ++ct) {
      int n = ct * 16 + l15;
      int byte_off = n * 256 + (((kb * 64) + kq * 16) ^ ((n & 7) << 4));
      short8 b = *(const short8*)((const char*)w1s + byte_off);
      acc[ct] = __builtin_amdgcn_mfma_f32_16x16x32_bf16(a, b, acc[ct], 0, 0, 0);
    }
  }
  #pragma unroll
  for (int ct = 0; ct < 8; ++ct) {
    #pragma unroll
    for (int r = 0; r < 4; ++r) {
      int orow = n0 + kq * 4 + r;
      gh8[(size_t)orow * 128 + ct * 16 + l15] = f2fp8(acc[ct][r]);
    }
  }
}

__global__ __launch_bounds__(256) void k_scanA(const int* __restrict__ counts,
                                               int* __restrict__ partials,
                                               int n, int chunk) {
  __shared__ int red[256];
  int b = blockIdx.x, t = threadIdx.x;
  int idx = b * chunk + t;
  red[t] = (t < chunk && idx < n) ? counts[idx] : 0;
  __syncthreads();
  for (int off = 128; off > 0; off >>= 1) {
    if (t < off) red[t] += red[t + off];
    __syncthreads();
  }
  if (t == 0) partials[b] = red[0];
}

__global__ __launch_bounds__(256) void k_scanC2(const int* __restrict__ counts,
                                                const int* __restrict__ partials,
                                                int* __restrict__ row_start,
                                                int n, int chunk, int total) {
  __shared__ int bp[256];
  __shared__ int p[256];
  int b = blockIdx.x, t = threadIdx.x;
  bp[t] = partials[t];
  __syncthreads();
  #pragma unroll
  for (int off = 1; off < 256; off <<= 1) {
    int v = (t >= off) ? bp[t - off] : 0;
    __syncthreads();
    bp[t] += v;
    __syncthreads();
  }
  int base = (b == 0) ? 0 : bp[b - 1];
  int idx = b * chunk + t;
  bool ok = (t < chunk && idx < n);
  int orig = ok ? counts[idx] : 0;
  p[t] = orig;
  __syncthreads();
  #pragma unroll
  for (int off = 1; off < 256; off <<= 1) {
    int v = (t >= off) ? p[t - off] : 0;
    __syncthreads();
    p[t] += v;
    __syncthreads();
  }
  if (ok) row_start[idx] = base + p[t] - orig;
  if (b == 0 && t == 0) row_start[n] = total;
}

__global__ __launch_bounds__(256) void k_fill0(const int* __restrict__ src,
                                               const int* __restrict__ dst,
                                               const int* __restrict__ row_start,
                                               const int* __restrict__ rank,
                                               int* __restrict__ bsrc,
                                               int n_edges) {
  int i = blockIdx.x * blockDim.x + threadIdx.x;
  int stride = gridDim.x * blockDim.x;
  for (int e = i; e < n_edges; e += stride) {
    bsrc[row_start[dst[e]] + rank[e]] = src[e];
  }
}

// one dst per 16-lane sub; chunks of 8: uniform index loads -> 8 gathers in flight
__global__ __launch_bounds__(256) void k_att2(const uint2* __restrict__ gh8v,
                                              const int* __restrict__ bsrc,
                                              const int* __restrict__ row_start,
                                              const float* __restrict__ b1,
                                              const float* __restrict__ W2,
                                              const float* __restrict__ b2,
                                              int2* __restrict__ bucket,
                                              float* __restrict__ denom,
                                              int n_nodes) {
  int lane = threadIdx.x & 63;
  int sub = lane >> 4, l16 = lane & 15;
  int wavei = threadIdx.x >> 6;
  int d = blockIdx.x * 16 + wavei * 4 + sub;
  int beg = 0, end = 0;
  if (d < n_nodes) { beg = row_start[d]; end = row_start[d + 1]; }
  float4 b1a = *(const float4*)&b1[l16 * 8];
  float4 b1b = *(const float4*)&b1[l16 * 8 + 4];
  AttC K;
  K.w2a = *(const float4*)&W2[l16 * 8];
  K.w2b = *(const float4*)&W2[l16 * 8 + 4];
  float b2v = b2[0];
  K.c0 = K.c1 = K.c2 = K.c3 = K.c4 = K.c5 = K.c6 = K.c7 = 0.f;
  if (beg < end) {
    uint2 ud = gh8v[(size_t)d * 16 + l16];
    float2 da = fp8x2<false>(ud.x), db = fp8x2<true>(ud.x);
    float2 dc = fp8x2<false>(ud.y), dd = fp8x2<true>(ud.y);
    K.c0 = b1a.x - da.x; K.c1 = b1a.y - da.y; K.c2 = b1a.z - db.x; K.c3 = b1a.w - db.y;
    K.c4 = b1b.x - dc.x; K.c5 = b1b.y - dc.y; K.c6 = b1b.z - dd.x; K.c7 = b1b.w - dd.y;
  }
  uint nn = (uint)n_nodes;
  for (int base = beg; base < end; base += 8) {
    // uniform (sub-wide same-address) index loads; register-resident addresses
    int s0 = bsrc[base + 0], s1 = bsrc[base + 1];
    int s2 = bsrc[base + 2], s3 = bsrc[base + 3];
    int s4 = bsrc[base + 4], s5 = bsrc[base + 5];
    int s6 = bsrc[base + 6], s7 = bsrc[base + 7];
    s0 = ((uint)s0 < nn) ? s0 : 0;  s1 = ((uint)s1 < nn) ? s1 : 0;
    s2 = ((uint)s2 < nn) ? s2 : 0;  s3 = ((uint)s3 < nn) ? s3 : 0;
    s4 = ((uint)s4 < nn) ? s4 : 0;  s5 = ((uint)s5 < nn) ? s5 : 0;
    s6 = ((uint)s6 < nn) ? s6 : 0;  s7 = ((uint)s7 < nn) ? s7 : 0;
    // 8 independent row gathers, all issued before any compute
    uint2 u0 = gh8v[(size_t)s0 * 16 + l16];
    uint2 u1 = gh8v[(size_t)s1 * 16 + l16];
    uint2 u2 = gh8v[(size_t)s2 * 16 + l16];
    uint2 u3 = gh8v[(size_t)s3 * 16 + l16];
    uint2 u4 = gh8v[(size_t)s4 * 16 + l16];
    uint2 u5 = gh8v[(size_t)s5 * 16 + l16];
    uint2 u6 = gh8v[(size_t)s6 * 16 + l16];
    uint2 u7 = gh8v[(size_t)s7 * 16 + l16];
    float a0 = dpp_red16(edge_logit(u0, K));
    float a1 = dpp_red16(edge_logit(u1, K));
    float a2 = dpp_red16(edge_logit(u2, K));
    float a3 = dpp_red16(edge_logit(u3, K));
    float a4 = dpp_red16(edge_logit(u4, K));
    float a5 = dpp_red16(edge_logit(u5, K));
    float a6 = dpp_red16(edge_logit(u6, K));
    float a7 = dpp_red16(edge_logit(u7, K));
    if (l16 == 0) {
      float aa[8] = {a0, a1, a2, a3, a4, a5, a6, a7};
      int ss[8] = {s0, s1, s2, s3, s4, s5, s6, s7};
      #pragma unroll
      for (int j = 0; j < 8; ++j) {
        if (base + j < end) {
          float a = fmaxf(aa[j] + b2v, 0.f);
          a = 1.f / (1.f + __expf(-a));
          bucket[base + j] = make_int2(ss[j], __float_as_int(a));
          atomicAdd(&denom[ss[j]], a);
        }
      }
    }
  }
}

// hh[s] *= 1/denom[s] in place (node-parallel, coalesced)
__global__ __launch_bounds__(256) void k_norm(uint4* __restrict__ hh4,
                                              const float* __restrict__ denom,
                                              int n_nodes) {
  int i = blockIdx.x * 256 + threadIdx.x;   // over n_nodes*16 uint4s
  if (i >= n_nodes * 16) return;
  int node = i >> 4;
  float inv = 1.f / denom[node];
  uint4 v = hh4[i];
  float2 f0 = unpack_f16(v.x), f1 = unpack_f16(v.y);
  float2 f2 = unpack_f16(v.z), f3 = unpack_f16(v.w);
  v.x = pack_f16(f0.x * inv, f0.y * inv);
  v.y = pack_f16(f1.x * inv, f1.y * inv);
  v.z = pack_f16(f2.x * inv, f2.y * inv);
  v.w = pack_f16(f3.x * inv, f3.y * inv);
  hh4[i] = v;
}

// one dst per sub; chunks of 8: uniform bucket loads -> 8 hh gathers in flight
__global__ __launch_bounds__(256) void k_agg(const uint4* __restrict__ hh4,
                                             const int* __restrict__ row_start,
                                             const int2* __restrict__ bucket,
                                             float* __restrict__ out, int n_nodes) {
  int lane = threadIdx.x & 63;
  int sub = lane >> 4, l16 = lane & 15;
  int wavei = threadIdx.x >> 6;
  int d = blockIdx.x * 16 + wavei * 4 + sub;
  int beg = 0, end = 0;
  if (d < n_nodes) { beg = row_start[d]; end = row_start[d + 1]; }
  float a0 = 0.f, a1 = 0.f, a2 = 0.f, a3 = 0.f;
  float a4 = 0.f, a5 = 0.f, a6 = 0.f, a7 = 0.f;
  uint nn = (uint)n_nodes;
  for (int base = beg; base < end; base += 8) {
    int2 e0 = bucket[base + 0], e1 = bucket[base + 1];
    int2 e2 = bucket[base + 2], e3 = bucket[base + 3];
    int2 e4 = bucket[base + 4], e5 = bucket[base + 5];
    int2 e6 = bucket[base + 6], e7 = bucket[base + 7];
    int s0 = ((uint)e0.x < nn) ? e0.x : 0;  int s1 = ((uint)e1.x < nn) ? e1.x : 0;
    int s2 = ((uint)e2.x < nn) ? e2.x : 0;  int s3 = ((uint)e3.x < nn) ? e3.x : 0;
    int s4 = ((uint)e4.x < nn) ? e4.x : 0;  int s5 = ((uint)e5.x < nn) ? e5.x : 0;
    int s6 = ((uint)e6.x < nn) ? e6.x : 0;  int s7 = ((uint)e7.x < nn) ? e7.x : 0;
    uint4 v0 = hh4[(size_t)s0 * 16 + l16];
    uint4 v1 = hh4[(size_t)s1 * 16 + l16];
    uint4 v2 = hh4[(size_t)s2 * 16 + l16];
    uint4 v3 = hh4[(size_t)s3 * 16 + l16];
    uint4 v4 = hh4[(size_t)s4 * 16 + l16];
    uint4 v5 = hh4[(size_t)s5 * 16 + l16];
    uint4 v6 = hh4[(size_t)s6 * 16 + l16];
    uint4 v7 = hh4[(size_t)s7 * 16 + l16];
    float w0 = (base + 0 < end) ? __int_as_float(e0.y) : 0.f;
    float w1 = (base + 1 < end) ? __int_as_float(e1.y) : 0.f;
    float w2 = (base + 2 < end) ? __int_as_float(e2.y) : 0.f;
    float w3 = (base + 3 < end) ? __int_as_float(e3.y) : 0.f;
    float w4 = (base + 4 < end) ? __int_as_float(e4.y) : 0.f;
    float w5 = (base + 5 < end) ? __int_as_float(e5.y) : 0.f;
    float w6 = (base + 6 < end) ? __int_as_float(e6.y) : 0.f;
    float w7 = (base + 7 < end) ? __int_as_float(e7.y) : 0.f;
    accv(w0, v0, a0, a1, a2, a3, a4, a5, a6, a7);
    accv(w1, v1, a0, a1, a2, a3, a4, a5, a6, a7);
    accv(w2, v2, a0, a1, a2, a3, a4, a5, a6, a7);
    accv(w3, v3, a0, a1, a2, a3, a4, a5, a6, a7);
    accv(w4, v4, a0, a1, a2, a3, a4, a5, a6, a7);
    accv(w5, v5, a0, a1, a2, a3, a4, a5, a6, a7);
    accv(w6, v6, a0, a1, a2, a3, a4, a5, a6, a7);
    accv(w7, v7, a0, a1, a2, a3, a4, a5, a6, a7);
  }
  if (d < n_nodes) {
    *(float4*)&out[(size_t)d * 128 + l16 * 8]     = make_float4(a0, a1, a2, a3);
    *(float4*)&out[(size_t)d * 128 + l16 * 8 + 4] = make_float4(a4, a5, a6, a7);
  }
}

extern "C" void kernel_launch(void* const* d_in, const int* in_sizes, int n_in,
                              void* d_out, int out_size, void* d_ws, size_t ws_size,
                              hipStream_t stream) {
  const float* h   = (const float*)d_in[0];
  const int*   src = (const int*)d_in[1];
  const int*   dst = (const int*)d_in[2];
  const float* W1  = (const float*)d_in[3];
  const float* b1  = (const float*)d_in[4];
  const float* W2  = (const float*)d_in[5];
  const float* b2  = (const float*)d_in[6];
  float* out = (float*)d_out;

  int n_nodes = in_sizes[0] / 128;
  int n_edges = in_sizes[1];

  char* ws = (char*)d_ws;
  uchar*  gh8       = (uchar*)ws;                           // n*128 bytes (fp8 rows)
  uint*   hh        = (uint*)(ws + (size_t)n_nodes * 128);  // n*64 uints (fp16 rows)
  float*  denom     = (float*)(hh + (size_t)n_nodes * 64);  // n
  int*    counts    = (int*)(denom + n_nodes);              // n
  int*    row_start = counts + n_nodes;                     // n+1
  int*    partials  = row_start + n_nodes + 1;              // 256
  ushort* w1t       = (ushort*)(partials + 256);            // 16384 (32 KiB)
  int2*   bucket    = (int2*)(((uintptr_t)(w1t + 16384) + 15) & ~(uintptr_t)15);  // E
  int*    bsrc      = (int*)(bucket + n_edges);             // E
  int*    rank      = bsrc + n_edges;                       // E (bsrc chunk overreads land here)

  int chunk = (n_nodes + 255) / 256;
  int n_tiles = (n_nodes + 15) / 16;
  int gemm_blocks = (n_tiles + 3) / 4;
  int nblk16 = (n_nodes + 15) / 16;
  k_prep  <<<64 + 16, 256, 0, stream>>>(W1, w1t, (int*)denom, 2 * n_nodes);
  k_gemm  <<<gemm_blocks + 256, 256, 0, stream>>>(h, w1t, gh8, (uint4*)hh, n_nodes,
                                                  dst, counts, rank, n_edges, gemm_blocks);
  k_scanA <<<256, 256, 0, stream>>>(counts, partials, n_nodes, chunk);
  k_scanC2<<<256, 256, 0, stream>>>(counts, partials, row_start, n_nodes, chunk, n_edges);
  k_fill0 <<<1024, 256, 0, stream>>>(src, dst, row_start, rank, bsrc, n_edges);
  k_att2  <<<nblk16, 256, 0, stream>>>((const uint2*)gh8, bsrc, row_start, b1, W2, b2,
                                       bucket, denom, n_nodes);
  k_norm  <<<(n_nodes * 16 + 255) / 256, 256, 0, stream>>>((uint4*)hh, denom, n_nodes);
  k_agg   <<<nblk16, 256, 0, stream>>>((const uint4*)hh, row_start, bucket, out, n_nodes);
}